// Round 3
// baseline (387.050 us; speedup 1.0000x reference)
//
#include <hip/hip_runtime.h>

// x_t = a_t * x_{t-1} + u_t ; B=8, T=4096, D=1024, fp32.
// 3-pass chunked scan.
// R5: R3's source-level load batching was re-fused by the compiler (VGPR 36,
// dur unchanged, 1.35 TB/s). This version forces the pipeline with inline asm:
//  - 512-thread blocks, float2/thread => 8192 waves (32/CU cap vs 16 before)
//  - asm global_load_dwordx2 batches (CH=4 steps, 8 loads in flight), double
//    buffered, counted s_waitcnt vmcnt(N) (8 in pass1; 12 in pass3 = next
//    batch 8 loads + prev iter 4 stores), sched_barrier(0) after each wait,
//    keep-alive asm to pin store-source regs until retirement.
#define BB 8
#define TT 4096
#define DD 1024
#define SS 128            // segments along T
#define TSEG (TT / SS)    // 32 timesteps per segment
#define STR2 (DD / 2)     // natf2 row stride
#define CH 4              // timesteps per batch
#define NB (TSEG / CH)    // 8 batches

typedef float natf2 __attribute__((ext_vector_type(2)));

#define GLOAD2(dst, ptr) \
  asm volatile("global_load_dwordx2 %0, %1, off" : "=v"(dst) : "v"(ptr))
#define GSTORE2(ptr, val) \
  asm volatile("global_store_dwordx2 %0, %1, off" ::"v"(ptr), "v"(val) : "memory")
#define SWAITV(n) asm volatile("s_waitcnt vmcnt(" #n ")" ::: "memory")
#define KEEP(v) asm volatile("" ::"v"(v))

// ---------------------------------------------------------------------------
// Pass 1: per-segment affine summary (A = prod a, U = zero-init scan).
// Block = one (b, s), 512 threads, 2 channels/thread. Asm-forced 8-deep load
// pipeline; one counted vmcnt(8) per batch keeps the next batch in flight.
// ---------------------------------------------------------------------------
__global__ __launch_bounds__(512) void seg_reduce(
    const float* __restrict__ a, const float* __restrict__ u,
    float* __restrict__ wsA, float* __restrict__ wsU) {
  const int b = blockIdx.x >> 7;        // / SS
  const int s = blockIdx.x & (SS - 1);
  const int d2 = threadIdx.x << 1;

  const size_t base = ((size_t)b * TT + (size_t)s * TSEG) * DD + d2;
  const natf2* __restrict__ ap = (const natf2*)(a + base);
  const natf2* __restrict__ up = (const natf2*)(u + base);

  natf2 av[2][CH], uv[2][CH];
#pragma unroll
  for (int k = 0; k < CH; ++k) {
    GLOAD2(av[0][k], ap + (size_t)k * STR2);
    GLOAD2(uv[0][k], up + (size_t)k * STR2);
  }

  natf2 A = {1.f, 1.f};
  natf2 U = {0.f, 0.f};

#pragma unroll
  for (int i = 0; i < NB; ++i) {
    const int pb = i & 1;
    if (i + 1 < NB) {
#pragma unroll
      for (int k = 0; k < CH; ++k) {
        GLOAD2(av[pb ^ 1][k], ap + (size_t)((i + 1) * CH + k) * STR2);
        GLOAD2(uv[pb ^ 1][k], up + (size_t)((i + 1) * CH + k) * STR2);
      }
      SWAITV(8);   // batch i retired; batch i+1 (8 newest) stays in flight
    } else {
      SWAITV(0);   // last batch: drain
    }
    __builtin_amdgcn_sched_barrier(0);  // rule #18: no hoist above the wait
#pragma unroll
    for (int k = 0; k < CH; ++k) {
      const natf2 a2 = av[pb][k], u2 = uv[pb][k];
      U.x = fmaf(a2.x, U.x, u2.x);
      U.y = fmaf(a2.y, U.y, u2.y);
      A.x *= a2.x;
      A.y *= a2.y;
    }
  }

  const size_t w = ((size_t)b * SS + s) * DD + d2;
  *(natf2*)(wsA + w) = A;
  *(natf2*)(wsU + w) = U;
}

// ---------------------------------------------------------------------------
// Pass 2: scan across segment summaries. Unchanged (small fraction of time).
// ---------------------------------------------------------------------------
__global__ __launch_bounds__(256) void seg_scan(
    const float* __restrict__ x0, const float* __restrict__ wsA,
    const float* __restrict__ wsU, float* __restrict__ xstart) {
  __shared__ float ldsA[SS * 64];       // [s][ch] : 32 KiB
  __shared__ float ldsU[SS * 64];       // 32 KiB
  __shared__ float wsumA[4][64];        // per-wave chunk transform
  __shared__ float wsumU[4][64];

  const int b  = blockIdx.x >> 4;       // 16 channel-groups per b
  const int d0 = (blockIdx.x & 15) << 6;
  const int ch = threadIdx.x & 63;
  const int wv = threadIdx.x >> 6;      // 0..3

#pragma unroll 8
  for (int it = 0; it < SS / 4; ++it) {
    const int s = (it << 2) + wv;
    const size_t g = ((size_t)b * SS + s) * DD + d0 + ch;
    ldsA[s * 64 + ch] = wsA[g];
    ldsU[s * 64 + ch] = wsU[g];
  }
  __syncthreads();

  float Ac = 1.f, Uc = 0.f;
  const int s0 = wv * (SS / 4);
#pragma unroll 8
  for (int k = 0; k < SS / 4; ++k) {
    const float As = ldsA[(s0 + k) * 64 + ch];
    const float Us = ldsU[(s0 + k) * 64 + ch];
    Uc = fmaf(As, Uc, Us);
    Ac *= As;
  }
  wsumA[wv][ch] = Ac;
  wsumU[wv][ch] = Uc;
  __syncthreads();

  float x = x0[(size_t)b * DD + d0 + ch];
  for (int w2 = 0; w2 < wv; ++w2)
    x = fmaf(wsumA[w2][ch], x, wsumU[w2][ch]);

#pragma unroll 8
  for (int k = 0; k < SS / 4; ++k) {
    const int s = s0 + k;
    xstart[((size_t)b * SS + s) * DD + d0 + ch] = x;
    x = fmaf(ldsA[s * 64 + ch], x, ldsU[s * 64 + ch]);
  }
}

// ---------------------------------------------------------------------------
// Pass 3: replay each segment from its entry state. Same asm pipeline; counted
// vmcnt(12) = next batch's 8 loads + previous iter's 4 stores, which (by
// in-order vmcnt retirement) also guarantees the parity store buffer being
// rewritten this iteration has retired. Stores via asm; KEEP pins the store
// source regs until the wait that proves retirement.
// ---------------------------------------------------------------------------
__global__ __launch_bounds__(512) void seg_apply(
    const float* __restrict__ a, const float* __restrict__ u,
    const float* __restrict__ xstart, float* __restrict__ out) {
  const int b = blockIdx.x >> 7;
  const int s = blockIdx.x & (SS - 1);
  const int d2 = threadIdx.x << 1;

  const size_t base = ((size_t)b * TT + (size_t)s * TSEG) * DD + d2;
  const natf2* __restrict__ ap = (const natf2*)(a + base);
  const natf2* __restrict__ up = (const natf2*)(u + base);
  natf2* __restrict__ op = (natf2*)(out + base);

  const size_t w = ((size_t)b * SS + s) * DD + d2;
  natf2 x = *(const natf2*)(xstart + w);

  natf2 av[2][CH], uv[2][CH], sv[2][CH];
#pragma unroll
  for (int k = 0; k < CH; ++k) {
    GLOAD2(av[0][k], ap + (size_t)k * STR2);
    GLOAD2(uv[0][k], up + (size_t)k * STR2);
  }

#pragma unroll
  for (int i = 0; i < NB; ++i) {
    const int pb = i & 1;
    if (i + 1 < NB) {
#pragma unroll
      for (int k = 0; k < CH; ++k) {
        GLOAD2(av[pb ^ 1][k], ap + (size_t)((i + 1) * CH + k) * STR2);
        GLOAD2(uv[pb ^ 1][k], up + (size_t)((i + 1) * CH + k) * STR2);
      }
      if (i == 0) { SWAITV(8); } else { SWAITV(12); }
    } else {
      SWAITV(4);   // newest 4 = prev iter's stores; all loads retired
    }
    __builtin_amdgcn_sched_barrier(0);
    if (i >= 2) {
      // stores issued 2 iters ago into sv[pb] are retired by the wait above;
      // pin their regs alive until here so the compiler couldn't reuse them.
#pragma unroll
      for (int k = 0; k < CH; ++k) KEEP(sv[pb][k]);
    }
#pragma unroll
    for (int k = 0; k < CH; ++k) {
      const natf2 a2 = av[pb][k], u2 = uv[pb][k];
      x.x = fmaf(a2.x, x.x, u2.x);
      x.y = fmaf(a2.y, x.y, u2.y);
      sv[pb][k] = x;
      GSTORE2(op + (size_t)(i * CH + k) * STR2, sv[pb][k]);
    }
  }
  // final drain: last two batches' store sources must stay live to retirement
  SWAITV(0);
#pragma unroll
  for (int k = 0; k < CH; ++k) { KEEP(sv[0][k]); KEEP(sv[1][k]); }
}

extern "C" void kernel_launch(void* const* d_in, const int* in_sizes, int n_in,
                              void* d_out, int out_size, void* d_ws, size_t ws_size,
                              hipStream_t stream) {
  const float* x0 = (const float*)d_in[0];  // [B, D]
  const float* a  = (const float*)d_in[1];  // [B, T, D]
  const float* u  = (const float*)d_in[2];  // [B, T, D]
  float* out = (float*)d_out;               // [B, T, D]

  const size_t seg_elems = (size_t)BB * SS * DD;  // 1M floats = 4 MiB
  float* wsA    = (float*)d_ws;
  float* wsU    = wsA + seg_elems;
  float* xstart = wsU + seg_elems;

  seg_reduce<<<BB * SS, 512, 0, stream>>>(a, u, wsA, wsU);
  seg_scan<<<BB * (DD / 64), 256, 0, stream>>>(x0, wsA, wsU, xstart);
  seg_apply<<<BB * SS, 512, 0, stream>>>(a, u, xstart, out);
}

// Round 4
// 372.440 us; speedup vs baseline: 1.0392x; 1.0392x over previous
//
#include <hip/hip_runtime.h>
#include <stdint.h>

// x_t = a_t * x_{t-1} + u_t ; B=8, T=4096, D=1024, fp32.
// 3-pass chunked scan.
// R6: R5's asm 8-deep reg pipeline changed nothing (106us, 1.35 TB/s, same as
// serial R0) => per-wave MLP/TLP exonerated. Delivered BW pinned at ~2.5 TB/s
// with ~6800cy effective latency => memory-system queuing. This round: LDS-
// staged streaming, global_load_lds width=16, 128 KiB double-buffered LDS,
// persistent 2-segment blocks. 64 KB/CU continuously in flight (2.3x R5),
// raw s_barrier + counted vmcnt (never 0 mid-loop). Discriminates "in-flight
// deficit" (=> ~2x win) vs "address-comb camping" (=> pinned, next = repack).
#define BB 8
#define TT 4096
#define DD 1024
#define SS 128            // segments along T
#define TSEG 32           // timesteps per segment
#define SPB 2             // segments per block (passes 1/3)
#define ROWS (SPB * TSEG) // 64 rows per block
#define CHR 8             // rows per chunk (32 KB per array)
#define NCH (ROWS / CHR)  // 8 chunks per block
#define GRID13 (BB * SS / SPB)  // 512 blocks

typedef float natf2 __attribute__((ext_vector_type(2)));
typedef const void __attribute__((address_space(1))) gvoid;
typedef void __attribute__((address_space(3))) lvoid;

#define SWAITV(n) asm volatile("s_waitcnt vmcnt(" #n ")" ::: "memory")
#define GLOAD2(dst, ptr) \
  asm volatile("global_load_dwordx2 %0, %1, off" : "=v"(dst) : "v"(ptr))
#define GSTORE2(ptr, val) \
  asm volatile("global_store_dwordx2 %0, %1, off" ::"v"(ptr), "v"(val) : "memory")
#define KEEP(v) asm volatile("" ::"v"(v))

// async global->LDS, 16B per lane. LDS dest must be wave-uniform base
// (HW adds lane*16); global src is per-lane.
static __device__ __forceinline__ void gload16(const float* g, float* l) {
  __builtin_amdgcn_global_load_lds((gvoid*)g, (lvoid*)l, 16, 0, 0);
}

// ---------------------------------------------------------------------------
// Pass 1: per-segment affine summary (A = prod a, U = zero-init scan).
// Block = (b, 2 consecutive segments), 512 threads. Chunks of 8 rows staged
// into LDS via 8 global_load_lds_dwordx4 per thread-slice; double-buffered;
// SWAITV(8) keeps next chunk's 64 KB in flight across the barrier.
// ---------------------------------------------------------------------------
__global__ __launch_bounds__(512) void seg_reduce(
    const float* __restrict__ a, const float* __restrict__ u,
    float* __restrict__ wsA, float* __restrict__ wsU) {
  __shared__ float lds[2][2][CHR][DD];  // [buf][arr][row][d] = 128 KiB
  const int tid = threadIdx.x;
  const int b  = blockIdx.x >> 6;       // 64 block-groups per b
  const int sg = blockIdx.x & 63;       // 2 segments each
  const int d2 = tid << 1;
  const size_t row0 = (size_t)b * TT + (size_t)sg * ROWS;
  const float* ga = a + row0 * DD;
  const float* gu = u + row0 * DD;
  const int mb = tid & ~63;             // wave-uniform lane-base for LDS dest

  // prologue: stage chunk 0 (8 gload_lds per thread: 4 for a, 4 for u)
#pragma unroll
  for (int k = 0; k < 4; ++k)
    gload16(ga + (size_t)((k * 512 + tid) << 2), &lds[0][0][0][0] + ((k * 512 + mb) << 2));
#pragma unroll
  for (int k = 0; k < 4; ++k)
    gload16(gu + (size_t)((k * 512 + tid) << 2), &lds[0][1][0][0] + ((k * 512 + mb) << 2));

  float A0x = 1.f, A0y = 1.f, U0x = 0.f, U0y = 0.f;  // segment 0 summary
  float A1x = 1.f, A1y = 1.f, U1x = 0.f, U1y = 0.f;  // segment 1 summary

#pragma unroll
  for (int g = 0; g < NCH; ++g) {
    __builtin_amdgcn_s_barrier();       // all waves done reading buf[(g+1)&1]
    if (g + 1 < NCH) {
      const float* ca = ga + (size_t)(g + 1) * CHR * DD;
      const float* cu = gu + (size_t)(g + 1) * CHR * DD;
      float* la = &lds[(g + 1) & 1][0][0][0];
      float* lu = &lds[(g + 1) & 1][1][0][0];
#pragma unroll
      for (int k = 0; k < 4; ++k)
        gload16(ca + (size_t)((k * 512 + tid) << 2), la + ((k * 512 + mb) << 2));
#pragma unroll
      for (int k = 0; k < 4; ++k)
        gload16(cu + (size_t)((k * 512 + tid) << 2), lu + ((k * 512 + mb) << 2));
      SWAITV(8);                        // chunk g resident; chunk g+1 in flight
    } else {
      SWAITV(0);                        // last chunk: drain
    }
    __builtin_amdgcn_s_barrier();       // chunk g visible to all waves
    __builtin_amdgcn_sched_barrier(0);  // rule #18: nothing hoists above wait
#pragma unroll
    for (int r = 0; r < CHR; ++r) {
      const natf2 a2 = *(const natf2*)&lds[g & 1][0][r][d2];
      const natf2 u2 = *(const natf2*)&lds[g & 1][1][r][d2];
      if (g < NCH / 2) {                // g compile-time (unrolled): static
        U0x = fmaf(a2.x, U0x, u2.x); U0y = fmaf(a2.y, U0y, u2.y);
        A0x *= a2.x; A0y *= a2.y;
      } else {
        U1x = fmaf(a2.x, U1x, u2.x); U1y = fmaf(a2.y, U1y, u2.y);
        A1x *= a2.x; A1y *= a2.y;
      }
    }
  }

  const size_t w0 = ((size_t)b * SS + (size_t)sg * SPB) * DD + d2;
  natf2 t;
  t.x = A0x; t.y = A0y; *(natf2*)(wsA + w0) = t;
  t.x = U0x; t.y = U0y; *(natf2*)(wsU + w0) = t;
  t.x = A1x; t.y = A1y; *(natf2*)(wsA + w0 + DD) = t;
  t.x = U1x; t.y = U1y; *(natf2*)(wsU + w0 + DD) = t;
}

// ---------------------------------------------------------------------------
// Pass 2: scan across segment summaries. Unchanged (small fraction of time).
// ---------------------------------------------------------------------------
__global__ __launch_bounds__(256) void seg_scan(
    const float* __restrict__ x0, const float* __restrict__ wsA,
    const float* __restrict__ wsU, float* __restrict__ xstart) {
  __shared__ float ldsA[SS * 64];       // [s][ch] : 32 KiB
  __shared__ float ldsU[SS * 64];       // 32 KiB
  __shared__ float wsumA[4][64];
  __shared__ float wsumU[4][64];

  const int b  = blockIdx.x >> 4;
  const int d0 = (blockIdx.x & 15) << 6;
  const int ch = threadIdx.x & 63;
  const int wv = threadIdx.x >> 6;

#pragma unroll 8
  for (int it = 0; it < SS / 4; ++it) {
    const int s = (it << 2) + wv;
    const size_t g = ((size_t)b * SS + s) * DD + d0 + ch;
    ldsA[s * 64 + ch] = wsA[g];
    ldsU[s * 64 + ch] = wsU[g];
  }
  __syncthreads();

  float Ac = 1.f, Uc = 0.f;
  const int s0 = wv * (SS / 4);
#pragma unroll 8
  for (int k = 0; k < SS / 4; ++k) {
    const float As = ldsA[(s0 + k) * 64 + ch];
    const float Us = ldsU[(s0 + k) * 64 + ch];
    Uc = fmaf(As, Uc, Us);
    Ac *= As;
  }
  wsumA[wv][ch] = Ac;
  wsumU[wv][ch] = Uc;
  __syncthreads();

  float x = x0[(size_t)b * DD + d0 + ch];
  for (int w2 = 0; w2 < wv; ++w2)
    x = fmaf(wsumA[w2][ch], x, wsumU[w2][ch]);

#pragma unroll 8
  for (int k = 0; k < SS / 4; ++k) {
    const int s = s0 + k;
    xstart[((size_t)b * SS + s) * DD + d0 + ch] = x;
    x = fmaf(ldsA[s * 64 + ch], x, ldsU[s * 64 + ch]);
  }
}

// ---------------------------------------------------------------------------
// Pass 3: replay from entry states. Same staged structure + asm out-stores.
// Uniform vmcnt counts: steady iter queue = loads(g)[8] + stores(g-1)[8] +
// loads(g+1)[8] -> SWAITV(16) retires loads(g), keeps 16 newest in flight.
// xstart preloaded via asm (retired by iter-0's SWAITV(8)) so no compiler
// waitcnt pollutes the counted queue.
// ---------------------------------------------------------------------------
__global__ __launch_bounds__(512) void seg_apply(
    const float* __restrict__ a, const float* __restrict__ u,
    const float* __restrict__ xstart, float* __restrict__ out) {
  __shared__ float lds[2][2][CHR][DD];  // 128 KiB
  const int tid = threadIdx.x;
  const int b  = blockIdx.x >> 6;
  const int sg = blockIdx.x & 63;
  const int d2 = tid << 1;
  const size_t row0 = (size_t)b * TT + (size_t)sg * ROWS;
  const float* ga = a + row0 * DD;
  const float* gu = u + row0 * DD;
  float* gout = out + row0 * DD;
  const int mb = tid & ~63;

  // entry states for this block's 2 segments (asm loads -> counted queue)
  natf2 xs0, xs1;
  const float* xp = xstart + ((size_t)b * SS + (size_t)sg * SPB) * DD + d2;
  GLOAD2(xs0, xp);
  GLOAD2(xs1, xp + DD);

  // stage chunk 0
#pragma unroll
  for (int k = 0; k < 4; ++k)
    gload16(ga + (size_t)((k * 512 + tid) << 2), &lds[0][0][0][0] + ((k * 512 + mb) << 2));
#pragma unroll
  for (int k = 0; k < 4; ++k)
    gload16(gu + (size_t)((k * 512 + tid) << 2), &lds[0][1][0][0] + ((k * 512 + mb) << 2));

  natf2 x;
  natf2 sv0[CHR], sv1[CHR];             // parity store buffers (static idx)

#pragma unroll
  for (int g = 0; g < NCH; ++g) {
    __builtin_amdgcn_s_barrier();       // buf[(g+1)&1] free
    if (g + 1 < NCH) {
      const float* ca = ga + (size_t)(g + 1) * CHR * DD;
      const float* cu = gu + (size_t)(g + 1) * CHR * DD;
      float* la = &lds[(g + 1) & 1][0][0][0];
      float* lu = &lds[(g + 1) & 1][1][0][0];
#pragma unroll
      for (int k = 0; k < 4; ++k)
        gload16(ca + (size_t)((k * 512 + tid) << 2), la + ((k * 512 + mb) << 2));
#pragma unroll
      for (int k = 0; k < 4; ++k)
        gload16(cu + (size_t)((k * 512 + tid) << 2), lu + ((k * 512 + mb) << 2));
      if (g == 0) { SWAITV(8); }        // retires xs(2)+loads0(8); loads1 fly
      else        { SWAITV(16); }       // retires loads(g); stores(g-1)+loads(g+1) fly
    } else {
      SWAITV(8);                        // retires loads(7); stores(6) fly
    }
    __builtin_amdgcn_s_barrier();
    __builtin_amdgcn_sched_barrier(0);
    if (g >= 2) {                       // stores(g-2) retired by wait above:
#pragma unroll                          // parity buffer now safe to rewrite
      for (int r = 0; r < CHR; ++r) {
        if (g & 1) KEEP(sv1[r]); else KEEP(sv0[r]);
      }
    }
    if (g == 0) x = xs0;                // segment boundaries (g compile-time)
    if (g == NCH / 2) x = xs1;
#pragma unroll
    for (int r = 0; r < CHR; ++r) {
      const natf2 a2 = *(const natf2*)&lds[g & 1][0][r][d2];
      const natf2 u2 = *(const natf2*)&lds[g & 1][1][r][d2];
      x.x = fmaf(a2.x, x.x, u2.x);
      x.y = fmaf(a2.y, x.y, u2.y);
      if (g & 1) {
        sv1[r] = x;
        GSTORE2((natf2*)(gout + (size_t)(g * CHR + r) * DD + d2), sv1[r]);
      } else {
        sv0[r] = x;
        GSTORE2((natf2*)(gout + (size_t)(g * CHR + r) * DD + d2), sv0[r]);
      }
    }
  }
  SWAITV(0);                            // drain final stores
#pragma unroll
  for (int r = 0; r < CHR; ++r) { KEEP(sv0[r]); KEEP(sv1[r]); }
}

extern "C" void kernel_launch(void* const* d_in, const int* in_sizes, int n_in,
                              void* d_out, int out_size, void* d_ws, size_t ws_size,
                              hipStream_t stream) {
  const float* x0 = (const float*)d_in[0];  // [B, D]
  const float* a  = (const float*)d_in[1];  // [B, T, D]
  const float* u  = (const float*)d_in[2];  // [B, T, D]
  float* out = (float*)d_out;               // [B, T, D]

  const size_t seg_elems = (size_t)BB * SS * DD;  // 1M floats = 4 MiB
  float* wsA    = (float*)d_ws;
  float* wsU    = wsA + seg_elems;
  float* xstart = wsU + seg_elems;

  seg_reduce<<<GRID13, 512, 0, stream>>>(a, u, wsA, wsU);
  seg_scan<<<BB * (DD / 64), 256, 0, stream>>>(x0, wsA, wsU, xstart);
  seg_apply<<<GRID13, 512, 0, stream>>>(a, u, xstart, out);
}